// Round 14
// baseline (210.392 us; speedup 1.0000x reference)
//
#include <hip/hip_runtime.h>
#include <hip/hip_bf16.h>
#include <cmath>

// ---------------- problem constants ----------------
#define T_TOKENS 4096   // 2*2048
#define DMODEL   1024
#define HDIM     2048
#define NEXP     8
#define BM 128
#define BN 128
#define BK 32           // dbuf fits 32KB: As[2][128x32]+Bs[2][128x32]
#define MAXROWS 9216    // 8192 routed rows + worst-case per-expert padding to 128
#define MTILES_CAP 32   // max M-tiles one expert can need: 4096 rows / 128

typedef __bf16 bf16;
typedef __bf16 bf16x8 __attribute__((ext_vector_type(8)));
typedef __bf16 bf16x4 __attribute__((ext_vector_type(4)));
typedef float  f32x4  __attribute__((ext_vector_type(4)));

__device__ inline void gload_lds16(const void* g, void* l) {
  __builtin_amdgcn_global_load_lds(
      (const __attribute__((address_space(1))) void*)g,
      (__attribute__((address_space(3))) void*)l, 16, 0, 0);
}

// ---------------- router: logits -> softmax -> top2; also x -> bf16 ----------------
// NO atomics (R6 PMC: 8192 same-line atomicAdds ~= 100us serialized).
__global__ __launch_bounds__(256) void router_kernel(
    const float* __restrict__ x, const float* __restrict__ gw,
    bf16* __restrict__ xb, int* __restrict__ es, float* __restrict__ wsv)
{
  int wid = threadIdx.x >> 6, lane = threadIdx.x & 63;
  int t = blockIdx.x * 4 + wid;
  if (t >= T_TOKENS) return;
  const float* xrow = x + (size_t)t * DMODEL;

  double acc[NEXP];
#pragma unroll
  for (int e = 0; e < NEXP; e++) acc[e] = 0.0;

#pragma unroll
  for (int i = 0; i < 4; i++) {
    int d0 = (i * 64 + lane) * 4;
    float4 xv = *(const float4*)(xrow + d0);
    bf16x4 o = { (bf16)xv.x, (bf16)xv.y, (bf16)xv.z, (bf16)xv.w };
    *(bf16x4*)(xb + (size_t)t * DMODEL + d0) = o;
    const float* g0 = gw + (size_t)d0 * NEXP;
    float xs[4] = { xv.x, xv.y, xv.z, xv.w };
#pragma unroll
    for (int j = 0; j < 4; j++)
#pragma unroll
      for (int e = 0; e < NEXP; e++)
        acc[e] += (double)xs[j] * (double)g0[j * NEXP + e];
  }
#pragma unroll
  for (int e = 0; e < NEXP; e++) {
    double v = acc[e];
#pragma unroll
    for (int m = 32; m >= 1; m >>= 1) v += __shfl_xor(v, m, 64);
    acc[e] = v;
  }
  if (lane == 0) {
    float l[NEXP], p[NEXP];
    float mx = -1e30f;
#pragma unroll
    for (int e = 0; e < NEXP; e++) { l[e] = (float)acc[e]; mx = fmaxf(mx, l[e]); }
    float s = 0.f;
#pragma unroll
    for (int e = 0; e < NEXP; e++) { p[e] = __expf(l[e] - mx); s += p[e]; }
#pragma unroll
    for (int e = 0; e < NEXP; e++) p[e] /= s;
    int i0 = 0;
#pragma unroll
    for (int e = 1; e < NEXP; e++) if (p[e] > p[i0]) i0 = e;
    int i1 = (i0 == 0) ? 1 : 0;
#pragma unroll
    for (int e = 0; e < NEXP; e++) if (e != i0 && p[e] > p[i1]) i1 = e;
    float wA = p[i0], wB = p[i1];
    float dn = wA + wB + 1e-9f;
    wA /= dn; wB /= dn;
    es[t] = i0; es[T_TOKENS + t] = i1;
    wsv[t] = wA; wsv[T_TOKENS + t] = wB;
  }
}

// ---------------- setup: histogram + offsets + deterministic assignment ----------
__global__ __launch_bounds__(256) void setup_kernel(
    const int* __restrict__ es, int* __restrict__ off,
    int* __restrict__ perm, int* __restrict__ t2r)
{
  __shared__ int hist[256 * NEXP];
  __shared__ int offL[NEXP + 1];
  int tid = threadIdx.x;

  for (int i = tid; i < MAXROWS; i += 256) perm[i] = -1;

  int h[NEXP];
#pragma unroll
  for (int e = 0; e < NEXP; e++) h[e] = 0;
  int base = tid * 32;
#pragma unroll
  for (int k = 0; k < 32; k++) {
    int ev = es[base + k];
#pragma unroll
    for (int e = 0; e < NEXP; e++) h[e] += (ev == e);
  }
#pragma unroll
  for (int e = 0; e < NEXP; e++) hist[tid * NEXP + e] = h[e];
  __syncthreads();

  if (tid < NEXP) {
    int s = 0;
    for (int t = 0; t < 256; t++) {
      int v = hist[t * NEXP + tid];
      hist[t * NEXP + tid] = s;
      s += v;
    }
    offL[tid] = s;
  }
  __syncthreads();
  if (tid == 0) {
    int o = 0;
    int tot[NEXP];
#pragma unroll
    for (int e = 0; e < NEXP; e++) tot[e] = offL[e];
#pragma unroll
    for (int e = 0; e < NEXP; e++) {
      offL[e] = o;
      off[e] = o;
      o += ((tot[e] + BM - 1) / BM) * BM;
    }
    offL[NEXP] = o;
    off[NEXP] = o;
  }
  __syncthreads();

  int run[NEXP];
#pragma unroll
  for (int e = 0; e < NEXP; e++) run[e] = offL[e] + hist[tid * NEXP + e];
#pragma unroll
  for (int k = 0; k < 32; k++) {
    int i = base + k;
    int ev = es[i];
    int row = 0;
#pragma unroll
    for (int e = 0; e < NEXP; e++) {
      if (ev == e) { row = run[e]; run[e] = row + 1; }
    }
    perm[row] = i & (T_TOKENS - 1);
    t2r[i] = row;
  }
}

// ---------------- fused weight transpose+cvt: both w1 and w2 in one launch --------
__global__ __launch_bounds__(256) void transpose_cvt2_kernel(
    const float* __restrict__ w1, bf16* __restrict__ w1t,
    const float* __restrict__ w2, bf16* __restrict__ w2t)
{
  __shared__ bf16 tile[64][66];
  int bid = blockIdx.x;
  const float* s; bf16* d; int C, R, r0, c0;
  if (bid < NEXP * 512) {
    int e = bid >> 9, t = bid & 511;
    s = w1 + (size_t)e * DMODEL * HDIM; d = w1t + (size_t)e * DMODEL * HDIM;
    R = DMODEL; C = HDIM;
    r0 = (t >> 5) * 64; c0 = (t & 31) * 64;
  } else {
    bid -= NEXP * 512;
    int e = bid >> 9, t = bid & 511;
    s = w2 + (size_t)e * HDIM * DMODEL; d = w2t + (size_t)e * HDIM * DMODEL;
    R = HDIM; C = DMODEL;
    r0 = (t >> 4) * 64; c0 = (t & 15) * 64;
  }
  int tr = threadIdx.x >> 4;
  int tc4 = (threadIdx.x & 15) * 4;
#pragma unroll
  for (int i = 0; i < 4; i++) {
    int r = tr + i * 16;
    float4 v = *(const float4*)(s + (size_t)(r0 + r) * C + c0 + tc4);
    tile[tc4 + 0][r] = (bf16)v.x;
    tile[tc4 + 1][r] = (bf16)v.y;
    tile[tc4 + 2][r] = (bf16)v.z;
    tile[tc4 + 3][r] = (bf16)v.w;
  }
  __syncthreads();
  int cc0 = threadIdx.x >> 3;
  int ch = (threadIdx.x & 7) * 8;
#pragma unroll
  for (int i = 0; i < 2; i++) {
    int cc = cc0 + i * 32;
    const unsigned int* rp = (const unsigned int*)&tile[cc][0];
    unsigned int u0 = rp[ch / 2 + 0];
    unsigned int u1 = rp[ch / 2 + 1];
    unsigned int u2 = rp[ch / 2 + 2];
    unsigned int u3 = rp[ch / 2 + 3];
    uint4 o = { u0, u1, u2, u3 };
    *(uint4*)(d + (size_t)(c0 + cc) * R + r0 + ch) = o;
  }
}

// ---------------- MFMA GEMM: R10 repaired — BK=32 dbuf in 32KB, counted vmcnt -----
// Per K-step: STAGE(t+1 -> buf^1) [4 loads/thread]; vmcnt(4) (waits only tile-t
// loads, which had the whole previous step to land -> ~zero wait); barrier;
// COMPUTE(t); barrier (buffer-reuse fence). Same 32KB/residency and 2 barriers/
// step as R8 (67us) — only the WAIT target changes (R8 drained just-issued
// loads, eating full latency serially every step).
// R10's two bugs fixed: (a) it still drained vmcnt(0); (b) 64B-row layout had
// 4.4e6 bank-conflict cycles -> swizzle byte^=(r&3)<<4, pre-swizzled source.
// Fragment reads: wave covers a contiguous 1KB bijectively -> conflict-free.
// Expert == XCD mapping retained (R8: FETCH = unique bytes).
template<int KDIM, int NDIM, bool GELU>
__global__ __launch_bounds__(256) void moe_gemm_kernel(
    const bf16* __restrict__ A, const bf16* __restrict__ W,
    bf16* __restrict__ dst, const int* __restrict__ perm,
    const int* __restrict__ off)
{
  constexpr int NTN = NDIM / BN;           // 16 (G1) or 8 (G2)
  constexpr int LOG2NTN = (NTN == 16) ? 4 : 3;
  constexpr int NT = KDIM / BK;            // 32 (G1) or 64 (G2)
  int e  = blockIdx.x & 7;                 // expert == XCD
  int r  = blockIdx.x >> 3;
  int nt = r & (NTN - 1);
  int mtl = r >> LOG2NTN;
  int rowbase = off[e];
  int nrows = off[e + 1] - rowbase;
  if (mtl * BM >= nrows) return;           // idle block (imbalance slack)
  int row0 = rowbase + mtl * BM;
  int n0 = nt * BN;
  const bf16* Wb = W + (size_t)e * NDIM * KDIM;

  __shared__ bf16 As[2][BM * BK];          // 2 x 8 KB
  __shared__ bf16 Bs[2][BN * BK];          // 2 x 8 KB -> 32 KB total

  int tid = threadIdx.x;
  int lane = tid & 63;
  int wid = tid >> 6;
  int wm = wid >> 1, wn = wid & 1;
  int l15 = lane & 15;
  int hi16 = (lane >> 4) << 4;             // k-octet byte offset within 64B row

  int sr = tid >> 2;                       // staging row 0..63 (+64i)
  int sc4 = tid & 3;                       // 16B slot within 64B row
  int scol = (sc4 ^ (sr & 3)) * 8;         // inverse-swizzled global col (elems)

  unsigned arow[2];
#pragma unroll
  for (int i = 0; i < 2; i++) {
    int rr = sr + i * 64;
    unsigned g;
    if (GELU) { int p = perm[row0 + rr]; g = (p < 0) ? 0u : (unsigned)p; }
    else      { g = (unsigned)(row0 + rr); }
    arow[i] = g * (unsigned)KDIM;
  }
  unsigned brow[2];
#pragma unroll
  for (int i = 0; i < 2; i++) brow[i] = (unsigned)(n0 + sr + i * 64) * KDIM;

  f32x4 acc[4][4];
#pragma unroll
  for (int m = 0; m < 4; m++)
#pragma unroll
    for (int n = 0; n < 4; n++) acc[m][n] = (f32x4){0.f, 0.f, 0.f, 0.f};

  // gload_lds dest: offset = tid*16 -> wave-uniform base + lane*16  (required)
#define STAGE(bb, t) do {                                                    \
    int k0_ = (t) * BK;                                                      \
    _Pragma("unroll")                                                        \
    for (int i = 0; i < 2; i++)                                              \
      gload_lds16(A + arow[i] + k0_ + scol,                                  \
                  &As[bb][((sr + i * 64) * BK) + sc4 * 8]);                  \
    _Pragma("unroll")                                                        \
    for (int i = 0; i < 2; i++)                                              \
      gload_lds16(Wb + brow[i] + k0_ + scol,                                 \
                  &Bs[bb][((sr + i * 64) * BK) + sc4 * 8]);                  \
  } while (0)

#define COMPUTE(bb) do {                                                     \
    const char* asB = (const char*)&As[bb][0];                               \
    const char* bsB = (const char*)&Bs[bb][0];                               \
    bf16x8 af[4], bfr[4];                                                    \
    _Pragma("unroll")                                                        \
    for (int m = 0; m < 4; m++) {                                            \
      int rr = wm * 64 + m * 16 + l15;                                       \
      af[m] = *(const bf16x8*)(asB + rr * 64 + (hi16 ^ ((rr & 3) << 4)));    \
    }                                                                        \
    _Pragma("unroll")                                                        \
    for (int n = 0; n < 4; n++) {                                            \
      int rr = wn * 64 + n * 16 + l15;                                       \
      bfr[n] = *(const bf16x8*)(bsB + rr * 64 + (hi16 ^ ((rr & 3) << 4)));   \
    }                                                                        \
    _Pragma("unroll")                                                        \
    for (int m = 0; m < 4; m++)                                              \
      _Pragma("unroll")                                                      \
      for (int n = 0; n < 4; n++)                                            \
        acc[m][n] = __builtin_amdgcn_mfma_f32_16x16x32_bf16(af[m], bfr[n], acc[m][n], 0, 0, 0); \
  } while (0)

  STAGE(0, 0);
  int cur = 0;
  for (int t = 0; t < NT; ++t) {
    if (t + 1 < NT) {
      STAGE(cur ^ 1, t + 1);                              // issue next tile
      asm volatile("s_waitcnt vmcnt(4)" ::: "memory");    // tile-t loads done (own)
    } else {
      asm volatile("s_waitcnt vmcnt(0)" ::: "memory");
    }
    __syncthreads();                                      // everyone's tile-t done
    COMPUTE(cur);
    __syncthreads();                                      // buf reuse fence
    cur ^= 1;
  }

#undef STAGE
#undef COMPUTE

  // epilogue: C/D layout col = lane&15, row = (lane>>4)*4 + j2 ; bf16 store
#pragma unroll
  for (int m = 0; m < 4; m++) {
    int rbase = row0 + wm * 64 + m * 16 + ((lane >> 4) << 2);
#pragma unroll
    for (int j2 = 0; j2 < 4; j2++) {
      unsigned rg = (unsigned)(rbase + j2);
#pragma unroll
      for (int n = 0; n < 4; n++) {
        float v = acc[m][n][j2];
        if (GELU) v = 0.5f * v * (1.0f + erff(v * 0.70710678118654752f));
        dst[(size_t)rg * NDIM + (n0 + wn * 64 + n * 16 + l15)] = (bf16)v;
      }
    }
  }
}

// ---------------- combine: out = bias + w0*y[r0] + w1*y[r1] ----------------
__global__ __launch_bounds__(256) void combine_kernel(
    const bf16* __restrict__ y, const int* __restrict__ t2r,
    const float* __restrict__ wsv, const float* __restrict__ bias,
    float* __restrict__ out)
{
  int t = blockIdx.x;
  int d = threadIdx.x * 4;
  int r0 = t2r[t], r1 = t2r[T_TOKENS + t];
  float w0 = wsv[t], w1 = wsv[T_TOKENS + t];
  bf16x4 a = *(const bf16x4*)(y + (size_t)r0 * DMODEL + d);
  bf16x4 b = *(const bf16x4*)(y + (size_t)r1 * DMODEL + d);
  float4 bs = *(const float4*)(bias + d);
  float4 o;
  o.x = bs.x + w0 * (float)a[0] + w1 * (float)b[0];
  o.y = bs.y + w0 * (float)a[1] + w1 * (float)b[1];
  o.z = bs.z + w0 * (float)a[2] + w1 * (float)b[2];
  o.w = bs.w + w0 * (float)a[3] + w1 * (float)b[3];
  *(float4*)(out + (size_t)t * DMODEL + d) = o;
}

// ---------------- host ----------------
extern "C" void kernel_launch(void* const* d_in, const int* in_sizes, int n_in,
                              void* d_out, int out_size, void* d_ws, size_t ws_size,
                              hipStream_t stream)
{
  const float* x    = (const float*)d_in[0];
  const float* gw   = (const float*)d_in[1];
  const float* w1   = (const float*)d_in[2];
  const float* w2   = (const float*)d_in[3];
  const float* bias = (const float*)d_in[4];
  float* out = (float*)d_out;

  char* ws = (char*)d_ws;
  size_t o = 0;
  auto alloc = [&](size_t bytes) {
    void* p = ws + o;
    o = (o + bytes + 255) & ~(size_t)255;
    return p;
  };
  bf16*  xb     = (bf16*) alloc((size_t)T_TOKENS * DMODEL * 2);       // 8 MB
  bf16*  w1t    = (bf16*) alloc((size_t)NEXP * HDIM * DMODEL * 2);    // 32 MB [E][H][D]
  bf16*  w2t    = (bf16*) alloc((size_t)NEXP * DMODEL * HDIM * 2);    // 32 MB [E][D][H]
  bf16*  hidden = (bf16*) alloc((size_t)MAXROWS * HDIM * 2);          // 37.7 MB
  int*   perm   = (int*)  alloc((size_t)MAXROWS * 4);
  int*   t2r    = (int*)  alloc((size_t)2 * T_TOKENS * 4);
  int*   es     = (int*)  alloc((size_t)2 * T_TOKENS * 4);
  float* wsv    = (float*)alloc((size_t)2 * T_TOKENS * 4);
  int*   offs   = (int*)  alloc(64);
  // y aliases w1t: w1t is dead after G1; G2 writes y before combine reads it.
  bf16*  y      = w1t;   // MAXROWS*DMODEL*2 = 18.9 MB <= 32 MB

  router_kernel<<<T_TOKENS / 4, 256, 0, stream>>>(x, gw, xb, es, wsv);
  setup_kernel<<<1, 256, 0, stream>>>(es, offs, perm, t2r);

  // both weight transposes in one launch (1024 tiles)
  transpose_cvt2_kernel<<<NEXP * 512 * 2, 256, 0, stream>>>(w1, w1t, w2, w2t);

  // G1: xb(perm rows) x w1t^T -> gelu -> hidden ; cap 32 M-tiles/expert
  moe_gemm_kernel<DMODEL, HDIM, true>
      <<<NEXP * MTILES_CAP * (HDIM / BN), 256, 0, stream>>>(
      xb, w1t, hidden, perm, offs);
  // G2: hidden x w2t^T -> y (plain bf16 rows)
  moe_gemm_kernel<HDIM, DMODEL, false>
      <<<NEXP * MTILES_CAP * (DMODEL / BN), 256, 0, stream>>>(
      hidden, w2t, y, perm, offs);

  combine_kernel<<<T_TOKENS, 256, 0, stream>>>(y, t2r, wsv, bias, out);
}

// Round 17
// 189.151 us; speedup vs baseline: 1.1123x; 1.1123x over previous
//
#include <hip/hip_runtime.h>
#include <hip/hip_bf16.h>
#include <cmath>

// ---------------- problem constants ----------------
#define T_TOKENS 4096   // 2*2048
#define DMODEL   1024
#define HDIM     2048
#define NEXP     8
#define BM 128
#define BN 128
#define BK 64
#define MAXROWS 9216    // 8192 routed rows + worst-case per-expert padding to 128
#define MTILES_CAP 32   // max M-tiles one expert can need: 4096 rows / 128

typedef __bf16 bf16;
typedef __bf16 bf16x8 __attribute__((ext_vector_type(8)));
typedef __bf16 bf16x4 __attribute__((ext_vector_type(4)));
typedef float  f32x4  __attribute__((ext_vector_type(4)));

__device__ inline void gload_lds16(const void* g, void* l) {
  __builtin_amdgcn_global_load_lds(
      (const __attribute__((address_space(1))) void*)g,
      (__attribute__((address_space(3))) void*)l, 16, 0, 0);
}

// ---------------- router: logits -> softmax -> top2; also x -> bf16 ----------------
// NO atomics (R6 PMC: 8192 same-line atomicAdds ~= 100us serialized).
__global__ __launch_bounds__(256) void router_kernel(
    const float* __restrict__ x, const float* __restrict__ gw,
    bf16* __restrict__ xb, int* __restrict__ es, float* __restrict__ wsv)
{
  int wid = threadIdx.x >> 6, lane = threadIdx.x & 63;
  int t = blockIdx.x * 4 + wid;
  if (t >= T_TOKENS) return;
  const float* xrow = x + (size_t)t * DMODEL;

  double acc[NEXP];
#pragma unroll
  for (int e = 0; e < NEXP; e++) acc[e] = 0.0;

#pragma unroll
  for (int i = 0; i < 4; i++) {
    int d0 = (i * 64 + lane) * 4;
    float4 xv = *(const float4*)(xrow + d0);
    bf16x4 o = { (bf16)xv.x, (bf16)xv.y, (bf16)xv.z, (bf16)xv.w };
    *(bf16x4*)(xb + (size_t)t * DMODEL + d0) = o;
    const float* g0 = gw + (size_t)d0 * NEXP;
    float xs[4] = { xv.x, xv.y, xv.z, xv.w };
#pragma unroll
    for (int j = 0; j < 4; j++)
#pragma unroll
      for (int e = 0; e < NEXP; e++)
        acc[e] += (double)xs[j] * (double)g0[j * NEXP + e];
  }
#pragma unroll
  for (int e = 0; e < NEXP; e++) {
    double v = acc[e];
#pragma unroll
    for (int m = 32; m >= 1; m >>= 1) v += __shfl_xor(v, m, 64);
    acc[e] = v;
  }
  if (lane == 0) {
    float l[NEXP], p[NEXP];
    float mx = -1e30f;
#pragma unroll
    for (int e = 0; e < NEXP; e++) { l[e] = (float)acc[e]; mx = fmaxf(mx, l[e]); }
    float s = 0.f;
#pragma unroll
    for (int e = 0; e < NEXP; e++) { p[e] = __expf(l[e] - mx); s += p[e]; }
#pragma unroll
    for (int e = 0; e < NEXP; e++) p[e] /= s;
    int i0 = 0;
#pragma unroll
    for (int e = 1; e < NEXP; e++) if (p[e] > p[i0]) i0 = e;
    int i1 = (i0 == 0) ? 1 : 0;
#pragma unroll
    for (int e = 0; e < NEXP; e++) if (e != i0 && p[e] > p[i1]) i1 = e;
    float wA = p[i0], wB = p[i1];
    float dn = wA + wB + 1e-9f;
    wA /= dn; wB /= dn;
    es[t] = i0; es[T_TOKENS + t] = i1;
    wsv[t] = wA; wsv[T_TOKENS + t] = wB;
  }
}

// ---------------- setup: histogram + offsets + deterministic assignment ----------
__global__ __launch_bounds__(256) void setup_kernel(
    const int* __restrict__ es, int* __restrict__ off,
    int* __restrict__ perm, int* __restrict__ t2r)
{
  __shared__ int hist[256 * NEXP];
  __shared__ int offL[NEXP + 1];
  int tid = threadIdx.x;

  for (int i = tid; i < MAXROWS; i += 256) perm[i] = -1;

  int h[NEXP];
#pragma unroll
  for (int e = 0; e < NEXP; e++) h[e] = 0;
  int base = tid * 32;
#pragma unroll
  for (int k = 0; k < 32; k++) {
    int ev = es[base + k];
#pragma unroll
    for (int e = 0; e < NEXP; e++) h[e] += (ev == e);
  }
#pragma unroll
  for (int e = 0; e < NEXP; e++) hist[tid * NEXP + e] = h[e];
  __syncthreads();

  if (tid < NEXP) {
    int s = 0;
    for (int t = 0; t < 256; t++) {
      int v = hist[t * NEXP + tid];
      hist[t * NEXP + tid] = s;
      s += v;
    }
    offL[tid] = s;
  }
  __syncthreads();
  if (tid == 0) {
    int o = 0;
    int tot[NEXP];
#pragma unroll
    for (int e = 0; e < NEXP; e++) tot[e] = offL[e];
#pragma unroll
    for (int e = 0; e < NEXP; e++) {
      offL[e] = o;
      off[e] = o;
      o += ((tot[e] + BM - 1) / BM) * BM;
    }
    offL[NEXP] = o;
    off[NEXP] = o;
  }
  __syncthreads();

  int run[NEXP];
#pragma unroll
  for (int e = 0; e < NEXP; e++) run[e] = offL[e] + hist[tid * NEXP + e];
#pragma unroll
  for (int k = 0; k < 32; k++) {
    int i = base + k;
    int ev = es[i];
    int row = 0;
#pragma unroll
    for (int e = 0; e < NEXP; e++) {
      if (ev == e) { row = run[e]; run[e] = row + 1; }
    }
    perm[row] = i & (T_TOKENS - 1);
    t2r[i] = row;
  }
}

// ---------------- fused weight transpose+cvt: both w1 and w2 in one launch --------
// w1 [E][1024][2048] -> w1t [E][2048][1024] : 16x32 tiles/expert (512)
// w2 [E][2048][1024] -> w2t [E][1024][2048] : 32x16 tiles/expert (512)
__global__ __launch_bounds__(256) void transpose_cvt2_kernel(
    const float* __restrict__ w1, bf16* __restrict__ w1t,
    const float* __restrict__ w2, bf16* __restrict__ w2t)
{
  __shared__ bf16 tile[64][66];
  int bid = blockIdx.x;
  const float* s; bf16* d; int C, R, r0, c0;
  if (bid < NEXP * 512) {
    int e = bid >> 9, t = bid & 511;
    s = w1 + (size_t)e * DMODEL * HDIM; d = w1t + (size_t)e * DMODEL * HDIM;
    R = DMODEL; C = HDIM;
    r0 = (t >> 5) * 64; c0 = (t & 31) * 64;
  } else {
    bid -= NEXP * 512;
    int e = bid >> 9, t = bid & 511;
    s = w2 + (size_t)e * HDIM * DMODEL; d = w2t + (size_t)e * HDIM * DMODEL;
    R = HDIM; C = DMODEL;
    r0 = (t >> 4) * 64; c0 = (t & 15) * 64;
  }
  int tr = threadIdx.x >> 4;
  int tc4 = (threadIdx.x & 15) * 4;
#pragma unroll
  for (int i = 0; i < 4; i++) {
    int r = tr + i * 16;
    float4 v = *(const float4*)(s + (size_t)(r0 + r) * C + c0 + tc4);
    tile[tc4 + 0][r] = (bf16)v.x;
    tile[tc4 + 1][r] = (bf16)v.y;
    tile[tc4 + 2][r] = (bf16)v.z;
    tile[tc4 + 3][r] = (bf16)v.w;
  }
  __syncthreads();
  int cc0 = threadIdx.x >> 3;
  int ch = (threadIdx.x & 7) * 8;
#pragma unroll
  for (int i = 0; i < 2; i++) {
    int cc = cc0 + i * 32;
    const unsigned int* rp = (const unsigned int*)&tile[cc][0];
    unsigned int u0 = rp[ch / 2 + 0];
    unsigned int u1 = rp[ch / 2 + 1];
    unsigned int u2 = rp[ch / 2 + 2];
    unsigned int u3 = rp[ch / 2 + 3];
    uint4 o = { u0, u1, u2, u3 };
    *(uint4*)(d + (size_t)(c0 + cc) * R + r0 + ch) = o;
  }
}

// ---------------- MFMA GEMM: expert-aligned XCD + T2 swizzle (proven optimum) ------
// 128x128x64 tile, 4 waves, single 32KB LDS, ~4 blk/CU. Expert == XCD (round-
// robin dispatch): per-XCD weight slab = its L2 (R8: FETCH = unique bytes).
// Ten GEMM variants tested across R1-R14; every deviation (64KB dbuf, 96-128KB
// deep pipelines, BK=32 dbuf +-counted-vmcnt, BM=256) lost 13-115%. This
// structure is the measured optimum: delivery-latency plateau at ~420 TF.
template<int KDIM, int NDIM, bool GELU>
__global__ __launch_bounds__(256) void moe_gemm_kernel(
    const bf16* __restrict__ A, const bf16* __restrict__ W,
    bf16* __restrict__ dst, const int* __restrict__ perm,
    const int* __restrict__ off)
{
  constexpr int NTN = NDIM / BN;           // 16 (G1) or 8 (G2)
  constexpr int LOG2NTN = (NTN == 16) ? 4 : 3;
  int e  = blockIdx.x & 7;                 // expert == XCD
  int r  = blockIdx.x >> 3;
  int nt = r & (NTN - 1);
  int mtl = r >> LOG2NTN;
  int rowbase = off[e];
  int nrows = off[e + 1] - rowbase;
  if (mtl * BM >= nrows) return;           // idle block (imbalance slack)
  int row0 = rowbase + mtl * BM;
  int n0 = nt * BN;
  const bf16* Wb = W + (size_t)e * NDIM * KDIM;

  __shared__ bf16 As[BM * BK];
  __shared__ bf16 Bs[BN * BK];

  int tid = threadIdx.x;
  int lane = tid & 63;
  int wid = tid >> 6;
  int wm = wid >> 1, wn = wid & 1;
  int l15 = lane & 15;
  int hi16 = (lane >> 4) << 4;

  int sr = tid >> 3;                       // staging row 0..31 (+32i)
  int sc8 = tid & 7;                       // LDS 16B slot
  int scol = (sc8 ^ (sr & 7)) * 8;         // inverse-swizzled global col (elems)

  unsigned arow[4];
#pragma unroll
  for (int i = 0; i < 4; i++) {
    int rr = sr + i * 32;
    unsigned g;
    if (GELU) { int p = perm[row0 + rr]; g = (p < 0) ? 0u : (unsigned)p; }
    else      { g = (unsigned)(row0 + rr); }
    arow[i] = g * (unsigned)KDIM;
  }
  unsigned brow[4];
#pragma unroll
  for (int i = 0; i < 4; i++) brow[i] = (unsigned)(n0 + sr + i * 32) * KDIM;

  f32x4 acc[4][4];
#pragma unroll
  for (int m = 0; m < 4; m++)
#pragma unroll
    for (int n = 0; n < 4; n++) acc[m][n] = (f32x4){0.f, 0.f, 0.f, 0.f};

  for (int k0 = 0; k0 < KDIM; k0 += BK) {
#pragma unroll
    for (int i = 0; i < 4; i++)
      gload_lds16(A + arow[i] + k0 + scol, &As[((sr + i * 32) * BK) + sc8 * 8]);
#pragma unroll
    for (int i = 0; i < 4; i++)
      gload_lds16(Wb + brow[i] + k0 + scol, &Bs[((sr + i * 32) * BK) + sc8 * 8]);
    asm volatile("s_waitcnt vmcnt(0)" ::: "memory");
    __syncthreads();

    const char* asB = (const char*)As;
    const char* bsB = (const char*)Bs;
#pragma unroll
    for (int kk = 0; kk < 2; kk++) {
      int kb = kk * 64 + hi16;             // byte col within 128B row
      bf16x8 af[4], bfr[4];
#pragma unroll
      for (int m = 0; m < 4; m++) {
        int rr = wm * 64 + m * 16 + l15;
        af[m] = *(const bf16x8*)(asB + rr * 128 + (kb ^ ((rr & 7) << 4)));
      }
#pragma unroll
      for (int n = 0; n < 4; n++) {
        int rr = wn * 64 + n * 16 + l15;
        bfr[n] = *(const bf16x8*)(bsB + rr * 128 + (kb ^ ((rr & 7) << 4)));
      }
#pragma unroll
      for (int m = 0; m < 4; m++)
#pragma unroll
        for (int n = 0; n < 4; n++)
          acc[m][n] = __builtin_amdgcn_mfma_f32_16x16x32_bf16(af[m], bfr[n], acc[m][n], 0, 0, 0);
    }
    __syncthreads();
  }

  // epilogue: C/D layout col = lane&15, row = (lane>>4)*4 + j2 ; bf16 store
#pragma unroll
  for (int m = 0; m < 4; m++) {
    int rbase = row0 + wm * 64 + m * 16 + ((lane >> 4) << 2);
#pragma unroll
    for (int j2 = 0; j2 < 4; j2++) {
      unsigned rg = (unsigned)(rbase + j2);
#pragma unroll
      for (int n = 0; n < 4; n++) {
        float v = acc[m][n][j2];
        if (GELU) v = 0.5f * v * (1.0f + erff(v * 0.70710678118654752f));
        dst[(size_t)rg * NDIM + (n0 + wn * 64 + n * 16 + l15)] = (bf16)v;
      }
    }
  }
}

// ---------------- combine: out = bias + w0*y[r0] + w1*y[r1] ----------------
__global__ __launch_bounds__(256) void combine_kernel(
    const bf16* __restrict__ y, const int* __restrict__ t2r,
    const float* __restrict__ wsv, const float* __restrict__ bias,
    float* __restrict__ out)
{
  int t = blockIdx.x;
  int d = threadIdx.x * 4;
  int r0 = t2r[t], r1 = t2r[T_TOKENS + t];
  float w0 = wsv[t], w1 = wsv[T_TOKENS + t];
  bf16x4 a = *(const bf16x4*)(y + (size_t)r0 * DMODEL + d);
  bf16x4 b = *(const bf16x4*)(y + (size_t)r1 * DMODEL + d);
  float4 bs = *(const float4*)(bias + d);
  float4 o;
  o.x = bs.x + w0 * (float)a[0] + w1 * (float)b[0];
  o.y = bs.y + w0 * (float)a[1] + w1 * (float)b[1];
  o.z = bs.z + w0 * (float)a[2] + w1 * (float)b[2];
  o.w = bs.w + w0 * (float)a[3] + w1 * (float)b[3];
  *(float4*)(out + (size_t)t * DMODEL + d) = o;
}

// ---------------- host ----------------
extern "C" void kernel_launch(void* const* d_in, const int* in_sizes, int n_in,
                              void* d_out, int out_size, void* d_ws, size_t ws_size,
                              hipStream_t stream)
{
  const float* x    = (const float*)d_in[0];
  const float* gw   = (const float*)d_in[1];
  const float* w1   = (const float*)d_in[2];
  const float* w2   = (const float*)d_in[3];
  const float* bias = (const float*)d_in[4];
  float* out = (float*)d_out;

  char* ws = (char*)d_ws;
  size_t o = 0;
  auto alloc = [&](size_t bytes) {
    void* p = ws + o;
    o = (o + bytes + 255) & ~(size_t)255;
    return p;
  };
  bf16*  xb     = (bf16*) alloc((size_t)T_TOKENS * DMODEL * 2);       // 8 MB
  bf16*  w1t    = (bf16*) alloc((size_t)NEXP * HDIM * DMODEL * 2);    // 32 MB [E][H][D]
  bf16*  w2t    = (bf16*) alloc((size_t)NEXP * DMODEL * HDIM * 2);    // 32 MB [E][D][H]
  bf16*  hidden = (bf16*) alloc((size_t)MAXROWS * HDIM * 2);          // 37.7 MB
  int*   perm   = (int*)  alloc((size_t)MAXROWS * 4);
  int*   t2r    = (int*)  alloc((size_t)2 * T_TOKENS * 4);
  int*   es     = (int*)  alloc((size_t)2 * T_TOKENS * 4);
  float* wsv    = (float*)alloc((size_t)2 * T_TOKENS * 4);
  int*   offs   = (int*)  alloc(64);
  // y aliases w1t: w1t is dead after G1; G2 writes y before combine reads it.
  bf16*  y      = w1t;   // MAXROWS*DMODEL*2 = 18.9 MB <= 32 MB

  router_kernel<<<T_TOKENS / 4, 256, 0, stream>>>(x, gw, xb, es, wsv);
  setup_kernel<<<1, 256, 0, stream>>>(es, offs, perm, t2r);

  // both weight transposes in one launch (1024 tiles)
  transpose_cvt2_kernel<<<NEXP * 512 * 2, 256, 0, stream>>>(w1, w1t, w2, w2t);

  // G1: xb(perm rows) x w1t^T -> gelu -> hidden ; cap 32 M-tiles/expert
  moe_gemm_kernel<DMODEL, HDIM, true>
      <<<NEXP * MTILES_CAP * (HDIM / BN), 256, 0, stream>>>(
      xb, w1t, hidden, perm, offs);
  // G2: hidden x w2t^T -> y (plain bf16 rows)
  moe_gemm_kernel<HDIM, DMODEL, false>
      <<<NEXP * MTILES_CAP * (DMODEL / BN), 256, 0, stream>>>(
      hidden, w2t, y, perm, offs);

  combine_kernel<<<T_TOKENS, 256, 0, stream>>>(y, t2r, wsv, bias, out);
}